// Round 11
// baseline (92.608 us; speedup 1.0000x reference)
//
#include <hip/hip_runtime.h>
#include <math.h>

typedef float f32x4 __attribute__((ext_vector_type(4)));

// Problem constants (fixed by the reference setup)
constexpr int Bb = 32;
constexpr int Ss = 2048;
constexpr int Hh = 1024;
constexpr int SC = 128;                // s-rows per block in fused kernel
constexpr int CPB = Ss / SC;           // 16 chunks per batch
constexpr int NBLK = Bb * CPB;         // 512 blocks (2 blocks/CU, one round)

// ---------------- Kernel A: h = hidden @ W_in^T (W read HBM-once) ------------
// Block p owns W rows [p*8, p*8+8). Thread t = (b = t&31, row di = t>>5):
// the 32 b-threads sharing a row broadcast-read the same W element (one fetch),
// each streams hidden[b] (128 KB total, L2-resident after first touch).
// Total W HBM traffic = 4 MiB exactly (vs ~32 MiB in the per-batch-group
// mapping: R9 showed moving the 8x re-read HBM->L2 doesn't help; this kills
// the 8x itself). No shuffles, no LDS.
__global__ __launch_bounds__(256) void gemv_h_kernel(const float* __restrict__ hidden,
                                                     const float* __restrict__ W,
                                                     float* __restrict__ h)
{
    int t  = threadIdx.x;
    int b  = t & 31;                   // batch
    int di = t >> 5;                   // 0..7
    int i  = blockIdx.x * 8 + di;      // W row / output index
    const f32x4* wr = reinterpret_cast<const f32x4*>(W + (size_t)i * Hh);
    const f32x4* hd = reinterpret_cast<const f32x4*>(hidden + (size_t)b * Hh);
    float acc = 0.f;
#pragma unroll 8
    for (int k = 0; k < Hh / 4; ++k) {
        f32x4 wv = wr[k];
        f32x4 hv = hd[k];
        acc += wv[0] * hv[0] + wv[1] * hv[1] + wv[2] * hv[2] + wv[3] * hv[3];
    }
    h[(size_t)b * Hh + i] = acc;
}

// ---------------- Kernel B: fused scores + online softmax + partial context ----
// R5-EXACT (best measured: 59.9 us total; five later variants all null/worse).
// Block = (batch b, chunk of SC=128 rows). 4 waves, 32 rows per wave = 8 quads,
// ping-pong register prefetch: loads for quad q+1 issued BEFORE compute of
// quad q (16 KiB in flight per wave through the serial dot -> shuffle-reduce
// -> exp -> ctx chain). Natural VGPR (~190), 2 waves/SIMD, no spills.
__global__ __launch_bounds__(256) void attn_partial_kernel(const float* __restrict__ enc,
                                                           const float* __restrict__ h,
                                                           float* __restrict__ scores,
                                                           float* __restrict__ pm,
                                                           float* __restrict__ pl,
                                                           float* __restrict__ pctx)
{
    int blk   = blockIdx.x;           // 0..NBLK-1
    int b     = blk >> 4;             // / CPB (CPB = 16)
    int chunk = blk & (CPB - 1);
    int s0    = chunk * SC;
    int tid   = threadIdx.x;
    int wave  = tid >> 6;
    int lane  = tid & 63;

    // h fragment for this lane (elements 4*lane + 256*k)
    float4 hf[4];
    const float4* h4 = reinterpret_cast<const float4*>(h + (size_t)b * Hh);
#pragma unroll
    for (int k = 0; k < 4; ++k) hf[k] = h4[lane + 64 * k];

    float m = -INFINITY;
    float l = 0.f;
    float4 ctx[4];
#pragma unroll
    for (int k = 0; k < 4; ++k) ctx[k] = make_float4(0.f, 0.f, 0.f, 0.f);

    const float4* ebase = reinterpret_cast<const float4*>(enc + ((size_t)b * Ss + s0 + wave * 32) * Hh);

#define LOADQ(EV, Q)                                                        \
    {                                                                       \
        _Pragma("unroll")                                                   \
        for (int r = 0; r < 4; ++r) {                                       \
            const float4* e4 = ebase + (size_t)((Q) * 4 + r) * (Hh / 4);    \
            _Pragma("unroll")                                               \
            for (int k = 0; k < 4; ++k) EV[r][k] = e4[lane + 64 * k];       \
        }                                                                   \
    }

#define COMPQ(EV, Q)                                                        \
    {                                                                       \
        float d[4];                                                         \
        _Pragma("unroll")                                                   \
        for (int r = 0; r < 4; ++r) {                                       \
            d[r] = 0.f;                                                     \
            _Pragma("unroll")                                               \
            for (int k = 0; k < 4; ++k)                                     \
                d[r] += EV[r][k].x * hf[k].x + EV[r][k].y * hf[k].y +       \
                        EV[r][k].z * hf[k].z + EV[r][k].w * hf[k].w;        \
        }                                                                   \
        _Pragma("unroll")                                                   \
        for (int off = 32; off > 0; off >>= 1) {                            \
            _Pragma("unroll")                                               \
            for (int r = 0; r < 4; ++r) d[r] += __shfl_xor(d[r], off, 64);  \
        }                                                                   \
        if (lane == 0) {                                                    \
            *reinterpret_cast<float4*>(scores + (size_t)b * Ss + s0 +       \
                                       wave * 32 + 4 * (Q)) =               \
                make_float4(d[0], d[1], d[2], d[3]);                        \
        }                                                                   \
        float mn = fmaxf(fmaxf(fmaxf(d[0], d[1]), fmaxf(d[2], d[3])), m);   \
        if (mn > m) {                                                       \
            float c = __expf(m - mn);                                       \
            l *= c;                                                         \
            _Pragma("unroll")                                               \
            for (int k = 0; k < 4; ++k) {                                   \
                ctx[k].x *= c; ctx[k].y *= c; ctx[k].z *= c; ctx[k].w *= c; \
            }                                                               \
            m = mn;                                                         \
        }                                                                   \
        float p[4];                                                         \
        _Pragma("unroll")                                                   \
        for (int r = 0; r < 4; ++r) p[r] = __expf(d[r] - m);                \
        l += (p[0] + p[1]) + (p[2] + p[3]);                                 \
        _Pragma("unroll")                                                   \
        for (int k = 0; k < 4; ++k) {                                       \
            _Pragma("unroll")                                               \
            for (int r = 0; r < 4; ++r) {                                   \
                ctx[k].x += p[r] * EV[r][k].x;                              \
                ctx[k].y += p[r] * EV[r][k].y;                              \
                ctx[k].z += p[r] * EV[r][k].z;                              \
                ctx[k].w += p[r] * EV[r][k].w;                              \
            }                                                               \
        }                                                                   \
    }

    float4 evA[4][4], evB[4][4];
    LOADQ(evA, 0);
#pragma unroll 1
    for (int qq = 0; qq < 3; ++qq) {
        LOADQ(evB, 2 * qq + 1);
        COMPQ(evA, 2 * qq);
        LOADQ(evA, 2 * qq + 2);
        COMPQ(evB, 2 * qq + 1);
    }
    LOADQ(evB, 7);
    COMPQ(evA, 6);
    COMPQ(evB, 7);
#undef LOADQ
#undef COMPQ

    // intra-block combine across 4 waves via LDS
    __shared__ float lds_ctx[4][Hh];   // 16 KiB
    __shared__ float lds_m[4], lds_l[4];
    float4* ldsrow = reinterpret_cast<float4*>(lds_ctx[wave]);
#pragma unroll
    for (int k = 0; k < 4; ++k) ldsrow[64 * k + lane] = ctx[k];
    if (lane == 0) { lds_m[wave] = m; lds_l[wave] = l; }
    __syncthreads();

    float M = fmaxf(fmaxf(lds_m[0], lds_m[1]), fmaxf(lds_m[2], lds_m[3]));
    float L = 0.f;
    float4 acc = make_float4(0.f, 0.f, 0.f, 0.f);
#pragma unroll
    for (int w = 0; w < 4; ++w) {
        float c = __expf(lds_m[w] - M);
        L += c * lds_l[w];
        float4 v = reinterpret_cast<float4*>(lds_ctx[w])[tid];
        acc.x += c * v.x; acc.y += c * v.y; acc.z += c * v.z; acc.w += c * v.w;
    }
    reinterpret_cast<float4*>(pctx + (size_t)blk * Hh)[tid] = acc;
    if (tid == 0) { pm[blk] = M; pl[blk] = L; }
}

// ---------------- Kernel CD: combine partials -> context, scores -> attn_w ----
// Blocks [0,128): combine (b = blk>>2, 256-wide H slice). Blocks [128,384):
// finish attn_w; every thread recomputes (M,L) from pm/pl (L2 broadcast, cheap)
// so there is no cross-block dependency.
__global__ __launch_bounds__(256) void combine_finish_kernel(const float* __restrict__ pm,
                                                             const float* __restrict__ pl,
                                                             const float* __restrict__ pctx,
                                                             const float* __restrict__ scores,
                                                             float* __restrict__ out_ctx,
                                                             float* __restrict__ attn_out)
{
    int blk = blockIdx.x;
    int tid = threadIdx.x;
    if (blk < 128) {
        int b = blk >> 2;
        int col = (blk & 3) * 256 + tid;
        const float* mrow = pm + (size_t)b * CPB;
        const float* lrow = pl + (size_t)b * CPB;
        float M = -INFINITY;
#pragma unroll
        for (int c = 0; c < CPB; ++c) M = fmaxf(M, mrow[c]);
        float e[CPB];
        float L = 0.f;
#pragma unroll
        for (int c = 0; c < CPB; ++c) {
            e[c] = __expf(mrow[c] - M);
            L += e[c] * lrow[c];
        }
        float acc = 0.f;
#pragma unroll 4
        for (int c = 0; c < CPB; ++c)
            acc += e[c] * pctx[((size_t)b * CPB + c) * Hh + col];
        out_ctx[(size_t)b * Hh + col] = acc / L;
    } else {
        int idx = (blk - 128) * 256 + tid;   // 0..B*S-1
        int b = idx >> 11;                   // / S
        const float* mrow = pm + (size_t)b * CPB;
        const float* lrow = pl + (size_t)b * CPB;
        float M = -INFINITY;
#pragma unroll
        for (int c = 0; c < CPB; ++c) M = fmaxf(M, mrow[c]);
        float L = 0.f;
#pragma unroll
        for (int c = 0; c < CPB; ++c) L += __expf(mrow[c] - M) * lrow[c];
        attn_out[idx] = __expf(scores[idx] - M) / L;
    }
}

extern "C" void kernel_launch(void* const* d_in, const int* in_sizes, int n_in,
                              void* d_out, int out_size, void* d_ws, size_t ws_size,
                              hipStream_t stream) {
    const float* hidden = (const float*)d_in[0];   // [B,H]
    const float* enc    = (const float*)d_in[1];   // [B,S,H]
    const float* W_in   = (const float*)d_in[2];   // [H,H]

    float* out_ctx  = (float*)d_out;               // [B,H]   context first
    float* out_attn = (float*)d_out + Bb * Hh;     // [B,S]

    float* ws     = (float*)d_ws;
    float* h      = ws;                            // B*H      = 32768
    float* scores = ws + 32768;                    // B*S      = 65536
    float* pm     = ws + 98304;                    // NBLK     = 512
    float* pl     = ws + 98816;                    // NBLK     = 512
    float* pctx   = ws + 99328;                    // NBLK*H   = 524288
    (void)in_sizes; (void)n_in; (void)out_size; (void)ws_size;

    // A: h = hidden @ W_in^T   (W-panel per block: W read from HBM exactly once)
    gemv_h_kernel<<<Hh / 8, 256, 0, stream>>>(hidden, W_in, h);
    // B: fused scores + online softmax + partial context (R5-exact)
    attn_partial_kernel<<<NBLK, 256, 0, stream>>>(enc, h, scores, pm, pl, pctx);
    // CD: combine -> context, and scores -> attn_w (no cross-block dependency)
    combine_finish_kernel<<<128 + (Bb * Ss) / 256, 256, 0, stream>>>(pm, pl, pctx, scores,
                                                                     out_ctx, out_attn);
}

// Round 12
// 59.801 us; speedup vs baseline: 1.5486x; 1.5486x over previous
//
#include <hip/hip_runtime.h>
#include <math.h>

// Problem constants (fixed by the reference setup)
constexpr int Bb = 32;
constexpr int Ss = 2048;
constexpr int Hh = 1024;
constexpr int SC = 128;                // s-rows per block in fused kernel
constexpr int CPB = Ss / SC;           // 16 chunks per batch
constexpr int NBLK = Bb * CPB;         // 512 blocks (= 256 CU x 2, one round)

// ---------------- Kernel A: h = hidden @ W_in^T ----------------
// Block = (output index i, group of 4 batches). i = blk & 1023 so the 8 blocks
// sharing W row i are 1024 apart -> same XCD -> W row fetched from HBM once.
__global__ __launch_bounds__(256) void gemv_h_kernel(const float* __restrict__ hidden,
                                                     const float* __restrict__ W,
                                                     float* __restrict__ h)
{
    int tid  = threadIdx.x;
    int wave = tid >> 6;
    int lane = tid & 63;
    int i  = blockIdx.x & (Hh - 1);    // 0..1023
    int bg = blockIdx.x >> 10;         // 0..7
    int b  = bg * 4 + wave;            // 0..31
    const float4* wr = reinterpret_cast<const float4*>(W + (size_t)i * Hh);
    const float4* hd = reinterpret_cast<const float4*>(hidden + (size_t)b * Hh);
    float d = 0.f;
#pragma unroll
    for (int k = 0; k < 4; ++k) {
        float4 wv = wr[lane + 64 * k];
        float4 hv = hd[lane + 64 * k];
        d += wv.x * hv.x + wv.y * hv.y + wv.z * hv.z + wv.w * hv.w;
    }
#pragma unroll
    for (int off = 32; off > 0; off >>= 1) d += __shfl_xor(d, off, 64);
    if (lane == 0) h[(size_t)b * Hh + i] = d;
}

// ---------------- Kernel B: fused scores + online softmax + partial context ----
// Block = (batch b, chunk of SC=128 rows). 4 waves, 32 rows per wave = 8 quads.
// Ping-pong register prefetch: loads for quad q+1 are issued BEFORE the compute
// of quad q, so each wave keeps 16 KiB in flight through its serial
// dot -> shuffle-reduce -> exp -> ctx chain. Static buffer indexing (evA/evB).
__global__ __launch_bounds__(256) void attn_partial_kernel(const float* __restrict__ enc,
                                                           const float* __restrict__ h,
                                                           float* __restrict__ scores,
                                                           float* __restrict__ pm,
                                                           float* __restrict__ pl,
                                                           float* __restrict__ pctx)
{
    int blk   = blockIdx.x;           // 0..NBLK-1
    int b     = blk >> 4;             // / CPB (CPB = 16)
    int chunk = blk & (CPB - 1);
    int s0    = chunk * SC;
    int tid   = threadIdx.x;
    int wave  = tid >> 6;
    int lane  = tid & 63;

    // h fragment for this lane (elements 4*lane + 256*k)
    float4 hf[4];
    const float4* h4 = reinterpret_cast<const float4*>(h + (size_t)b * Hh);
#pragma unroll
    for (int k = 0; k < 4; ++k) hf[k] = h4[lane + 64 * k];

    float m = -INFINITY;
    float l = 0.f;
    float4 ctx[4];
#pragma unroll
    for (int k = 0; k < 4; ++k) ctx[k] = make_float4(0.f, 0.f, 0.f, 0.f);

    const float4* ebase = reinterpret_cast<const float4*>(enc + ((size_t)b * Ss + s0 + wave * 32) * Hh);

#define LOADQ(EV, Q)                                                        \
    {                                                                       \
        _Pragma("unroll")                                                   \
        for (int r = 0; r < 4; ++r) {                                       \
            const float4* e4 = ebase + (size_t)((Q) * 4 + r) * (Hh / 4);    \
            _Pragma("unroll")                                               \
            for (int k = 0; k < 4; ++k) EV[r][k] = e4[lane + 64 * k];       \
        }                                                                   \
    }

#define COMPQ(EV, Q)                                                        \
    {                                                                       \
        float d[4];                                                         \
        _Pragma("unroll")                                                   \
        for (int r = 0; r < 4; ++r) {                                       \
            d[r] = 0.f;                                                     \
            _Pragma("unroll")                                               \
            for (int k = 0; k < 4; ++k)                                     \
                d[r] += EV[r][k].x * hf[k].x + EV[r][k].y * hf[k].y +       \
                        EV[r][k].z * hf[k].z + EV[r][k].w * hf[k].w;        \
        }                                                                   \
        _Pragma("unroll")                                                   \
        for (int off = 32; off > 0; off >>= 1) {                            \
            _Pragma("unroll")                                               \
            for (int r = 0; r < 4; ++r) d[r] += __shfl_xor(d[r], off, 64);  \
        }                                                                   \
        if (lane == 0) {                                                    \
            *reinterpret_cast<float4*>(scores + (size_t)b * Ss + s0 +       \
                                       wave * 32 + 4 * (Q)) =               \
                make_float4(d[0], d[1], d[2], d[3]);                        \
        }                                                                   \
        float mn = fmaxf(fmaxf(fmaxf(d[0], d[1]), fmaxf(d[2], d[3])), m);   \
        if (mn > m) {                                                       \
            float c = __expf(m - mn);                                       \
            l *= c;                                                         \
            _Pragma("unroll")                                               \
            for (int k = 0; k < 4; ++k) {                                   \
                ctx[k].x *= c; ctx[k].y *= c; ctx[k].z *= c; ctx[k].w *= c; \
            }                                                               \
            m = mn;                                                         \
        }                                                                   \
        float p[4];                                                         \
        _Pragma("unroll")                                                   \
        for (int r = 0; r < 4; ++r) p[r] = __expf(d[r] - m);                \
        l += (p[0] + p[1]) + (p[2] + p[3]);                                 \
        _Pragma("unroll")                                                   \
        for (int k = 0; k < 4; ++k) {                                       \
            _Pragma("unroll")                                               \
            for (int r = 0; r < 4; ++r) {                                   \
                ctx[k].x += p[r] * EV[r][k].x;                              \
                ctx[k].y += p[r] * EV[r][k].y;                              \
                ctx[k].z += p[r] * EV[r][k].z;                              \
                ctx[k].w += p[r] * EV[r][k].w;                              \
            }                                                               \
        }                                                                   \
    }

    float4 evA[4][4], evB[4][4];
    LOADQ(evA, 0);
#pragma unroll 1
    for (int qq = 0; qq < 3; ++qq) {
        LOADQ(evB, 2 * qq + 1);
        COMPQ(evA, 2 * qq);
        LOADQ(evA, 2 * qq + 2);
        COMPQ(evB, 2 * qq + 1);
    }
    LOADQ(evB, 7);
    COMPQ(evA, 6);
    COMPQ(evB, 7);
#undef LOADQ
#undef COMPQ

    // intra-block combine across 4 waves via LDS
    __shared__ float lds_ctx[4][Hh];   // 16 KiB
    __shared__ float lds_m[4], lds_l[4];
    float4* ldsrow = reinterpret_cast<float4*>(lds_ctx[wave]);
#pragma unroll
    for (int k = 0; k < 4; ++k) ldsrow[64 * k + lane] = ctx[k];
    if (lane == 0) { lds_m[wave] = m; lds_l[wave] = l; }
    __syncthreads();

    float M = fmaxf(fmaxf(lds_m[0], lds_m[1]), fmaxf(lds_m[2], lds_m[3]));
    float L = 0.f;
    float4 acc = make_float4(0.f, 0.f, 0.f, 0.f);
#pragma unroll
    for (int w = 0; w < 4; ++w) {
        float c = __expf(lds_m[w] - M);
        L += c * lds_l[w];
        float4 v = reinterpret_cast<float4*>(lds_ctx[w])[tid];
        acc.x += c * v.x; acc.y += c * v.y; acc.z += c * v.z; acc.w += c * v.w;
    }
    reinterpret_cast<float4*>(pctx + (size_t)blk * Hh)[tid] = acc;
    if (tid == 0) { pm[blk] = M; pl[blk] = L; }
}

// ---------------- Kernel CD: combine partials -> context, scores -> attn_w ----
// Blocks [0,128): combine (b = blk>>2, 256-wide H slice). Blocks [128,384):
// finish attn_w; every thread recomputes (M,L) from pm/pl (L2 broadcast, cheap)
// so there is no cross-block dependency.
__global__ __launch_bounds__(256) void combine_finish_kernel(const float* __restrict__ pm,
                                                             const float* __restrict__ pl,
                                                             const float* __restrict__ pctx,
                                                             const float* __restrict__ scores,
                                                             float* __restrict__ out_ctx,
                                                             float* __restrict__ attn_out)
{
    int blk = blockIdx.x;
    int tid = threadIdx.x;
    if (blk < 128) {
        int b = blk >> 2;
        int col = (blk & 3) * 256 + tid;
        const float* mrow = pm + (size_t)b * CPB;
        const float* lrow = pl + (size_t)b * CPB;
        float M = -INFINITY;
#pragma unroll
        for (int c = 0; c < CPB; ++c) M = fmaxf(M, mrow[c]);
        float e[CPB];
        float L = 0.f;
#pragma unroll
        for (int c = 0; c < CPB; ++c) {
            e[c] = __expf(mrow[c] - M);
            L += e[c] * lrow[c];
        }
        float acc = 0.f;
#pragma unroll 4
        for (int c = 0; c < CPB; ++c)
            acc += e[c] * pctx[((size_t)b * CPB + c) * Hh + col];
        out_ctx[(size_t)b * Hh + col] = acc / L;
    } else {
        int idx = (blk - 128) * 256 + tid;   // 0..B*S-1
        int b = idx >> 11;                   // / S
        const float* mrow = pm + (size_t)b * CPB;
        const float* lrow = pl + (size_t)b * CPB;
        float M = -INFINITY;
#pragma unroll
        for (int c = 0; c < CPB; ++c) M = fmaxf(M, mrow[c]);
        float L = 0.f;
#pragma unroll
        for (int c = 0; c < CPB; ++c) L += __expf(mrow[c] - M) * lrow[c];
        attn_out[idx] = __expf(scores[idx] - M) / L;
    }
}

extern "C" void kernel_launch(void* const* d_in, const int* in_sizes, int n_in,
                              void* d_out, int out_size, void* d_ws, size_t ws_size,
                              hipStream_t stream) {
    const float* hidden = (const float*)d_in[0];   // [B,H]
    const float* enc    = (const float*)d_in[1];   // [B,S,H]
    const float* W_in   = (const float*)d_in[2];   // [H,H]

    float* out_ctx  = (float*)d_out;               // [B,H]   context first
    float* out_attn = (float*)d_out + Bb * Hh;     // [B,S]

    float* ws     = (float*)d_ws;
    float* h      = ws;                            // B*H      = 32768
    float* scores = ws + 32768;                    // B*S      = 65536
    float* pm     = ws + 98304;                    // NBLK     = 512
    float* pl     = ws + 98816;                    // NBLK     = 512
    float* pctx   = ws + 99328;                    // NBLK*H   = 524288
    (void)in_sizes; (void)n_in; (void)out_size; (void)ws_size;

    // A: h = hidden @ W_in^T   (XCD-local W-row reuse)
    gemv_h_kernel<<<Hh * (Bb / 4), 256, 0, stream>>>(hidden, W_in, h);
    // B: fused scores + online softmax + partial context (single enc pass,
    //    4-quad ping-pong register prefetch — best measured configuration, R5)
    attn_partial_kernel<<<NBLK, 256, 0, stream>>>(enc, h, scores, pm, pl, pctx);
    // CD: combine -> context, and scores -> attn_w (no cross-block dependency)
    combine_finish_kernel<<<128 + (Bb * Ss) / 256, 256, 0, stream>>>(pm, pl, pctx, scores,
                                                                     out_ctx, out_attn);
}